// Round 1
// baseline (405.450 us; speedup 1.0000x reference)
//
#include <hip/hip_runtime.h>
#include <cstdint>

// Shapes: B=8, C=256, H=W=64 -> N=4096, d=32, groups=32 (8 ch/group)

typedef __bf16 bf16x8 __attribute__((ext_vector_type(8)));
typedef float f32x4 __attribute__((ext_vector_type(4)));
typedef unsigned int u32x4 __attribute__((ext_vector_type(4)));
typedef unsigned short u16x4 __attribute__((ext_vector_type(4)));
typedef unsigned short u16x8 __attribute__((ext_vector_type(8)));

#define DEVI __device__ __forceinline__

DEVI unsigned short f2bf(float f) {
    __bf16 h = (__bf16)f;               // RNE fptrunc
    return __builtin_bit_cast(unsigned short, h);
}

DEVI f32x4 mfma16(bf16x8 a, bf16x8 b, f32x4 c) {
    return __builtin_amdgcn_mfma_f32_16x16x32_bf16(a, b, c, 0, 0, 0);
}

// ---------------- weight pack fp32 -> bf16 ----------------
__global__ __launch_bounds__(256) void k_pack(
        const float* __restrict__ wq, const float* __restrict__ wk,
        const float* __restrict__ wv, const float* __restrict__ wp,
        unsigned short* __restrict__ bqk, unsigned short* __restrict__ bv,
        unsigned short* __restrict__ bp) {
    int i = blockIdx.x * 256 + threadIdx.x;        // grid 256 -> 65536 threads
    if (i < 8192)       bqk[i] = f2bf(wq[i]);      // rows 0..31 = Wq
    else if (i < 16384) bqk[i] = f2bf(wk[i - 8192]); // rows 32..63 = Wk
    bv[i] = f2bf(wv[i]);
    bp[i] = f2bf(wp[i]);
}

// ---------------- group norm -> h^T (B*N, C) bf16 ----------------
__global__ __launch_bounds__(256) void k_gnorm(
        const float* __restrict__ x, const float* __restrict__ gw,
        const float* __restrict__ gb, unsigned short* __restrict__ ht) {
    int bg = blockIdx.x;               // 256 blocks = 8 batches * 32 groups
    int b = bg >> 5, g = bg & 31;
    const float* xb = x + ((size_t)(b * 256 + g * 8)) * 4096;  // 8 contiguous rows
    int t = threadIdx.x;
    float s1 = 0.f, s2 = 0.f;
    for (int i = t; i < 32768; i += 256) {
        float v = xb[i];
        s1 += v; s2 += v * v;
    }
    #pragma unroll
    for (int off = 1; off < 64; off <<= 1) {
        s1 += __shfl_xor(s1, off);
        s2 += __shfl_xor(s2, off);
    }
    __shared__ float red[10];
    int wv_ = t >> 6;
    if ((t & 63) == 0) { red[wv_ * 2] = s1; red[wv_ * 2 + 1] = s2; }
    __syncthreads();
    if (t == 0) {
        float a = red[0] + red[2] + red[4] + red[6];
        float q = red[1] + red[3] + red[5] + red[7];
        float mean = a * (1.f / 32768.f);
        float var = q * (1.f / 32768.f) - mean * mean;
        red[8] = mean; red[9] = rsqrtf(var + 1e-5f);
    }
    __syncthreads();
    float mean = red[8], rstd = red[9];
    float wv8[8], bv8[8];
    #pragma unroll
    for (int c = 0; c < 8; c++) { wv8[c] = gw[g * 8 + c]; bv8[c] = gb[g * 8 + c]; }
    for (int n = t; n < 4096; n += 256) {
        u16x8 pk;
        #pragma unroll
        for (int c = 0; c < 8; c++) {
            float v = (xb[c * 4096 + n] - mean) * rstd * wv8[c] + bv8[c];
            pk[c] = f2bf(v);
        }
        *(u16x8*)(&ht[((size_t)(b * 4096 + n)) * 256 + g * 8]) = pk;  // 16B store
    }
}

// ---------------- GEMM  C[M x Ncols] = A[M x 256] * Bw[Ncols x 256]^T ----------------
// BM=128, BN=64, BK=64. 4 waves; wave w: rows [w*32, w*32+32) x 64 cols.
// EPI 0: bf16 row-major out (ldout).  EPI 1: bf16 transposed (Vt[b][o][n]).
// EPI 2: fp32 transposed + residual: out[b][o][n] = x + gamma*acc.
template <int EPI>
__global__ __launch_bounds__(256) void k_gemm(
        const unsigned short* __restrict__ A, const unsigned short* __restrict__ Bw,
        void* __restrict__ outp, const float* __restrict__ xres,
        const float* __restrict__ gamma, int ldout) {
    __shared__ unsigned short lA[128 * 72];   // rows padded 64->72 elems (conflict-free)
    __shared__ unsigned short lB[64 * 72];
    int t = threadIdx.x;
    int m0 = blockIdx.x * 128, n0 = blockIdx.y * 64;
    int w = t >> 6, lane = t & 63, l15 = lane & 15, quad = lane >> 4;
    f32x4 z4 = {0.f, 0.f, 0.f, 0.f};
    f32x4 acc[2][4];
    #pragma unroll
    for (int i = 0; i < 2; i++)
        #pragma unroll
        for (int j = 0; j < 4; j++) acc[i][j] = z4;

    for (int kb = 0; kb < 4; kb++) {
        // stage A tile: 128 rows x 64 elems = 1024 chunks of 16B
        #pragma unroll
        for (int i = 0; i < 4; i++) {
            int ch = i * 256 + t;
            int row = ch >> 3, col = (ch & 7) * 8;
            u32x4 v = *(const u32x4*)(A + (size_t)(m0 + row) * 256 + kb * 64 + col);
            *(u32x4*)(&lA[row * 72 + col]) = v;
        }
        // stage B tile: 64 rows x 64 elems = 512 chunks
        #pragma unroll
        for (int i = 0; i < 2; i++) {
            int ch = i * 256 + t;
            int row = ch >> 3, col = (ch & 7) * 8;
            u32x4 v = *(const u32x4*)(Bw + (size_t)(n0 + row) * 256 + kb * 64 + col);
            *(u32x4*)(&lB[row * 72 + col]) = v;
        }
        __syncthreads();
        #pragma unroll
        for (int ks = 0; ks < 2; ks++) {
            bf16x8 af[2], bfr[4];
            #pragma unroll
            for (int fr = 0; fr < 2; fr++)
                af[fr] = *(const bf16x8*)(&lA[(w * 32 + fr * 16 + l15) * 72 + ks * 32 + quad * 8]);
            #pragma unroll
            for (int fn = 0; fn < 4; fn++)
                bfr[fn] = *(const bf16x8*)(&lB[(fn * 16 + l15) * 72 + ks * 32 + quad * 8]);
            #pragma unroll
            for (int fr = 0; fr < 2; fr++)
                #pragma unroll
                for (int fn = 0; fn < 4; fn++)
                    acc[fr][fn] = mfma16(af[fr], bfr[fn], acc[fr][fn]);
        }
        __syncthreads();
    }

    if (EPI == 0) {
        unsigned short* out = (unsigned short*)outp;
        #pragma unroll
        for (int fr = 0; fr < 2; fr++)
            #pragma unroll
            for (int fn = 0; fn < 4; fn++)
                #pragma unroll
                for (int r = 0; r < 4; r++) {
                    int m = m0 + w * 32 + fr * 16 + quad * 4 + r;
                    int n = n0 + fn * 16 + l15;
                    out[(size_t)m * ldout + n] = f2bf(acc[fr][fn][r]);
                }
    } else if (EPI == 1) {
        unsigned short* out = (unsigned short*)outp;
        int b = m0 >> 12, nb = (m0 & 4095) + w * 32;
        #pragma unroll
        for (int fr = 0; fr < 2; fr++)
            #pragma unroll
            for (int fn = 0; fn < 4; fn++) {
                int o = n0 + fn * 16 + l15;
                int n = nb + fr * 16 + quad * 4;
                u16x4 pk;
                #pragma unroll
                for (int r = 0; r < 4; r++) pk[r] = f2bf(acc[fr][fn][r]);
                *(u16x4*)(&out[(((size_t)(b * 256 + o)) << 12) + n]) = pk;
            }
    } else {
        float* out = (float*)outp;
        float gm = gamma[0];
        int b = m0 >> 12, nb = (m0 & 4095) + w * 32;
        #pragma unroll
        for (int fr = 0; fr < 2; fr++)
            #pragma unroll
            for (int fn = 0; fn < 4; fn++) {
                int o = n0 + fn * 16 + l15;
                int n = nb + fr * 16 + quad * 4;
                size_t base = (((size_t)(b * 256 + o)) << 12) + n;
                f32x4 xv = *(const f32x4*)(xres + base);
                f32x4 ov;
                #pragma unroll
                for (int r = 0; r < 4; r++) ov[r] = xv[r] + gm * acc[fr][fn][r];
                *(f32x4*)(out + base) = ov;
            }
    }
}

// ---------------- flash attention ----------------
// QK: (B*N, 64) bf16 (q cols 0..31, k cols 32..63). Vt: (B, 256, N) bf16.
// Block: 64 q-rows, 4 waves x 16 rows. Bc=64 keys/tile, 64 tiles.
__global__ __launch_bounds__(256) void k_flash(
        const unsigned short* __restrict__ QK, const unsigned short* __restrict__ Vt,
        unsigned short* __restrict__ Oa) {
    int id = blockIdx.x;
    int b = id & 7, qt = id >> 3;      // batch <-> XCD affinity (round-robin dispatch)
    int t = threadIdx.x, w = t >> 6, lane = t & 63, l15 = lane & 15, quad = lane >> 4;
    __shared__ unsigned short lK[64 * 40];        // 64 keys x 32 dd (pad 32->40)
    __shared__ unsigned short lV[256 * 72];       // 256 o x 64 keys (pad 64->72)
    __shared__ unsigned short lP[4][16 * 72];     // per-wave P (16 rows x 64 keys)
    int q0 = qt * 64;
    bf16x8 qf = *(const bf16x8*)(QK + ((size_t)(b * 4096 + q0 + w * 16 + l15)) * 64 + quad * 8);
    f32x4 z4 = {0.f, 0.f, 0.f, 0.f};
    f32x4 O[16];
    #pragma unroll
    for (int i = 0; i < 16; i++) O[i] = z4;
    float m2[4] = {-1e30f, -1e30f, -1e30f, -1e30f};
    float l[4] = {0.f, 0.f, 0.f, 0.f};
    const float sc = 0.17677669529663687f * 1.4426950408889634f;  // 1/sqrt(32) * log2(e)

    for (int kt = 0; kt < 64; kt++) {
        {   // stage K tile: 64 rows x 32 elems = 256 chunks
            int key = t >> 2, c = (t & 3) * 8;
            u32x4 v = *(const u32x4*)(QK + ((size_t)(b * 4096 + kt * 64 + key)) * 64 + 32 + c);
            *(u32x4*)(&lK[key * 40 + c]) = v;
        }
        #pragma unroll
        for (int i = 0; i < 8; i++) {  // stage V tile: 256 rows x 64 elems = 2048 chunks
            int ch = i * 256 + t;
            int o = ch >> 3, c = (ch & 7) * 8;
            u32x4 v = *(const u32x4*)(Vt + (((size_t)(b * 256 + o)) << 12) + kt * 64 + c);
            *(u32x4*)(&lV[o * 72 + c]) = v;
        }
        __syncthreads();

        f32x4 S[4];
        #pragma unroll
        for (int f = 0; f < 4; f++) {
            bf16x8 kf = *(const bf16x8*)(&lK[(f * 16 + l15) * 40 + quad * 8]);
            S[f] = mfma16(qf, kf, z4);
        }
        #pragma unroll
        for (int f = 0; f < 4; f++)
            #pragma unroll
            for (int r = 0; r < 4; r++) S[f][r] *= sc;   // exp2 domain

        float alpha[4];
        #pragma unroll
        for (int r = 0; r < 4; r++) {
            float m_ = fmaxf(fmaxf(S[0][r], S[1][r]), fmaxf(S[2][r], S[3][r]));
            m_ = fmaxf(m_, __shfl_xor(m_, 1));
            m_ = fmaxf(m_, __shfl_xor(m_, 2));
            m_ = fmaxf(m_, __shfl_xor(m_, 4));
            m_ = fmaxf(m_, __shfl_xor(m_, 8));
            float mn = fmaxf(m2[r], m_);
            alpha[r] = exp2f(m2[r] - mn);
            m2[r] = mn;
        }
        #pragma unroll
        for (int f = 0; f < 4; f++)
            #pragma unroll
            for (int r = 0; r < 4; r++) S[f][r] = exp2f(S[f][r] - m2[r]);
        #pragma unroll
        for (int r = 0; r < 4; r++) {
            float s_ = S[0][r] + S[1][r] + S[2][r] + S[3][r];
            s_ += __shfl_xor(s_, 1);
            s_ += __shfl_xor(s_, 2);
            s_ += __shfl_xor(s_, 4);
            s_ += __shfl_xor(s_, 8);
            l[r] = l[r] * alpha[r] + s_;
        }
        #pragma unroll
        for (int c = 0; c < 16; c++)
            #pragma unroll
            for (int r = 0; r < 4; r++) O[c][r] *= alpha[r];

        // P: D-layout -> LDS -> A-layout (per-wave region, in-order DS, no barrier)
        #pragma unroll
        for (int f = 0; f < 4; f++)
            #pragma unroll
            for (int r = 0; r < 4; r++)
                lP[w][(quad * 4 + r) * 72 + f * 16 + l15] = f2bf(S[f][r]);

        #pragma unroll
        for (int ks = 0; ks < 2; ks++) {
            bf16x8 pa = *(const bf16x8*)(&lP[w][l15 * 72 + ks * 32 + quad * 8]);
            #pragma unroll
            for (int c = 0; c < 16; c++) {
                bf16x8 vf = *(const bf16x8*)(&lV[(c * 16 + l15) * 72 + ks * 32 + quad * 8]);
                O[c] = mfma16(pa, vf, O[c]);
            }
        }
        __syncthreads();   // protect lK/lV before next stage
    }

    float rl[4];
    #pragma unroll
    for (int r = 0; r < 4; r++) rl[r] = 1.f / l[r];
    #pragma unroll
    for (int c = 0; c < 16; c++)
        #pragma unroll
        for (int r = 0; r < 4; r++) {
            size_t row = (size_t)(b * 4096 + q0 + w * 16 + quad * 4 + r);
            Oa[row * 256 + c * 16 + l15] = f2bf(O[c][r] * rl[r]);
        }
}

// ---------------- launch ----------------
extern "C" void kernel_launch(void* const* d_in, const int* in_sizes, int n_in,
                              void* d_out, int out_size, void* d_ws, size_t ws_size,
                              hipStream_t stream) {
    const float* x  = (const float*)d_in[0];
    const float* nw = (const float*)d_in[1];
    const float* nb = (const float*)d_in[2];
    const float* wq = (const float*)d_in[3];
    const float* wk = (const float*)d_in[4];
    const float* wv = (const float*)d_in[5];
    const float* wp = (const float*)d_in[6];
    const float* gm = (const float*)d_in[7];

    char* p = (char*)d_ws;
    unsigned short* ht  = (unsigned short*)p; p += (size_t)32768 * 256 * 2;  // 16 MB
    unsigned short* qk  = (unsigned short*)p; p += (size_t)32768 * 64 * 2;   // 4 MB
    unsigned short* vt  = (unsigned short*)p; p += (size_t)8 * 256 * 4096 * 2; // 16 MB
    unsigned short* oa  = (unsigned short*)p; p += (size_t)32768 * 256 * 2;  // 16 MB
    unsigned short* bqk = (unsigned short*)p; p += 64 * 256 * 2;
    unsigned short* bv  = (unsigned short*)p; p += 256 * 256 * 2;
    unsigned short* bp  = (unsigned short*)p; p += 256 * 256 * 2;

    k_pack<<<dim3(256), dim3(256), 0, stream>>>(wq, wk, wv, wp, bqk, bv, bp);
    k_gnorm<<<dim3(256), dim3(256), 0, stream>>>(x, nw, nb, ht);
    k_gemm<0><<<dim3(256, 1), dim3(256), 0, stream>>>(ht, bqk, (void*)qk, nullptr, nullptr, 64);
    k_gemm<1><<<dim3(256, 4), dim3(256), 0, stream>>>(ht, bv, (void*)vt, nullptr, nullptr, 0);
    k_flash<<<dim3(512), dim3(256), 0, stream>>>(qk, vt, oa);
    k_gemm<2><<<dim3(256, 4), dim3(256), 0, stream>>>(oa, bp, d_out, x, gm, 0);
}

// Round 2
// 389.800 us; speedup vs baseline: 1.0401x; 1.0401x over previous
//
#include <hip/hip_runtime.h>
#include <cstdint>

// Shapes: B=8, C=256, H=W=64 -> N=4096, d=32, groups=32 (8 ch/group)

typedef __bf16 bf16x8 __attribute__((ext_vector_type(8)));
typedef float f32x4 __attribute__((ext_vector_type(4)));
typedef unsigned int u32x4 __attribute__((ext_vector_type(4)));
typedef unsigned short u16x4 __attribute__((ext_vector_type(4)));
typedef unsigned short u16x8 __attribute__((ext_vector_type(8)));

#define DEVI __device__ __forceinline__

DEVI unsigned short f2bf(float f) {
    __bf16 h = (__bf16)f;               // RNE fptrunc
    return __builtin_bit_cast(unsigned short, h);
}

DEVI f32x4 mfma16(bf16x8 a, bf16x8 b, f32x4 c) {
    return __builtin_amdgcn_mfma_f32_16x16x32_bf16(a, b, c, 0, 0, 0);
}

// async global->LDS, 16B per lane, wave-uniform LDS base + lane*16
DEVI void glds16(const unsigned short* g, unsigned short* l) {
    const __attribute__((address_space(1))) unsigned int* gp =
        reinterpret_cast<const __attribute__((address_space(1))) unsigned int*>(
            reinterpret_cast<uintptr_t>(g));
    __attribute__((address_space(3))) unsigned int* lp =
        reinterpret_cast<__attribute__((address_space(3))) unsigned int*>(
            reinterpret_cast<uintptr_t>(l));
    __builtin_amdgcn_global_load_lds(gp, lp, 16, 0, 0);
}

// log2(e)/sqrt(32): folded into Wq so S exits QK-MFMA in exp2 domain
#define QSCALE 0.2550663133f
#define MFIX   12.0f

// ---------------- weight pack fp32 -> bf16 ----------------
__global__ __launch_bounds__(256) void k_pack(
        const float* __restrict__ wq, const float* __restrict__ wk,
        const float* __restrict__ wv, const float* __restrict__ wp,
        unsigned short* __restrict__ bqk, unsigned short* __restrict__ bv,
        unsigned short* __restrict__ bp) {
    int i = blockIdx.x * 256 + threadIdx.x;        // grid 256 -> 65536 threads
    if (i < 8192)       bqk[i] = f2bf(wq[i] * QSCALE);   // rows 0..31 = Wq (pre-scaled)
    else if (i < 16384) bqk[i] = f2bf(wk[i - 8192]);     // rows 32..63 = Wk
    bv[i] = f2bf(wv[i]);
    bp[i] = f2bf(wp[i]);
}

// ---------------- group norm -> h^T (B*N, C) bf16 ----------------
__global__ __launch_bounds__(256) void k_gnorm(
        const float* __restrict__ x, const float* __restrict__ gw,
        const float* __restrict__ gb, unsigned short* __restrict__ ht) {
    int bg = blockIdx.x;               // 256 blocks = 8 batches * 32 groups
    int b = bg >> 5, g = bg & 31;
    const float* xb = x + ((size_t)(b * 256 + g * 8)) * 4096;  // 8 contiguous rows
    int t = threadIdx.x;
    float s1 = 0.f, s2 = 0.f;
    for (int i = t; i < 32768; i += 256) {
        float v = xb[i];
        s1 += v; s2 += v * v;
    }
    #pragma unroll
    for (int off = 1; off < 64; off <<= 1) {
        s1 += __shfl_xor(s1, off);
        s2 += __shfl_xor(s2, off);
    }
    __shared__ float red[10];
    int wv_ = t >> 6;
    if ((t & 63) == 0) { red[wv_ * 2] = s1; red[wv_ * 2 + 1] = s2; }
    __syncthreads();
    if (t == 0) {
        float a = red[0] + red[2] + red[4] + red[6];
        float q = red[1] + red[3] + red[5] + red[7];
        float mean = a * (1.f / 32768.f);
        float var = q * (1.f / 32768.f) - mean * mean;
        red[8] = mean; red[9] = rsqrtf(var + 1e-5f);
    }
    __syncthreads();
    float mean = red[8], rstd = red[9];
    float wv8[8], bv8[8];
    #pragma unroll
    for (int c = 0; c < 8; c++) { wv8[c] = gw[g * 8 + c]; bv8[c] = gb[g * 8 + c]; }
    for (int n = t; n < 4096; n += 256) {
        u16x8 pk;
        #pragma unroll
        for (int c = 0; c < 8; c++) {
            float v = (xb[c * 4096 + n] - mean) * rstd * wv8[c] + bv8[c];
            pk[c] = f2bf(v);
        }
        *(u16x8*)(&ht[((size_t)(b * 4096 + n)) * 256 + g * 8]) = pk;  // 16B store
    }
}

// ---------------- GEMM  C[M x Ncols] = A[M x 256] * Bw[Ncols x 256]^T ----------------
// BM=128, BN=64, BK=64. 4 waves; wave w: rows [w*32, w*32+32) x 64 cols.
// EPI 0: bf16 row-major out (ldout).  EPI 1: bf16 transposed (Vt[b][o][n]).
// EPI 2: fp32 transposed + residual: out[b][o][n] = x + gamma*acc.
template <int EPI>
__global__ __launch_bounds__(256) void k_gemm(
        const unsigned short* __restrict__ A, const unsigned short* __restrict__ Bw,
        void* __restrict__ outp, const float* __restrict__ xres,
        const float* __restrict__ gamma, int ldout) {
    __shared__ unsigned short lA[128 * 72];   // rows padded 64->72 elems
    __shared__ unsigned short lB[64 * 72];
    int t = threadIdx.x;
    int m0 = blockIdx.x * 128, n0 = blockIdx.y * 64;
    int w = t >> 6, lane = t & 63, l15 = lane & 15, quad = lane >> 4;
    f32x4 z4 = {0.f, 0.f, 0.f, 0.f};
    f32x4 acc[2][4];
    #pragma unroll
    for (int i = 0; i < 2; i++)
        #pragma unroll
        for (int j = 0; j < 4; j++) acc[i][j] = z4;

    for (int kb = 0; kb < 4; kb++) {
        #pragma unroll
        for (int i = 0; i < 4; i++) {
            int ch = i * 256 + t;
            int row = ch >> 3, col = (ch & 7) * 8;
            u32x4 v = *(const u32x4*)(A + (size_t)(m0 + row) * 256 + kb * 64 + col);
            *(u32x4*)(&lA[row * 72 + col]) = v;
        }
        #pragma unroll
        for (int i = 0; i < 2; i++) {
            int ch = i * 256 + t;
            int row = ch >> 3, col = (ch & 7) * 8;
            u32x4 v = *(const u32x4*)(Bw + (size_t)(n0 + row) * 256 + kb * 64 + col);
            *(u32x4*)(&lB[row * 72 + col]) = v;
        }
        __syncthreads();
        #pragma unroll
        for (int ks = 0; ks < 2; ks++) {
            bf16x8 af[2], bfr[4];
            #pragma unroll
            for (int fr = 0; fr < 2; fr++)
                af[fr] = *(const bf16x8*)(&lA[(w * 32 + fr * 16 + l15) * 72 + ks * 32 + quad * 8]);
            #pragma unroll
            for (int fn = 0; fn < 4; fn++)
                bfr[fn] = *(const bf16x8*)(&lB[(fn * 16 + l15) * 72 + ks * 32 + quad * 8]);
            #pragma unroll
            for (int fr = 0; fr < 2; fr++)
                #pragma unroll
                for (int fn = 0; fn < 4; fn++)
                    acc[fr][fn] = mfma16(af[fr], bfr[fn], acc[fr][fn]);
        }
        __syncthreads();
    }

    if (EPI == 0) {
        unsigned short* out = (unsigned short*)outp;
        #pragma unroll
        for (int fr = 0; fr < 2; fr++)
            #pragma unroll
            for (int fn = 0; fn < 4; fn++)
                #pragma unroll
                for (int r = 0; r < 4; r++) {
                    int m = m0 + w * 32 + fr * 16 + quad * 4 + r;
                    int n = n0 + fn * 16 + l15;
                    out[(size_t)m * ldout + n] = f2bf(acc[fr][fn][r]);
                }
    } else if (EPI == 1) {
        unsigned short* out = (unsigned short*)outp;
        int b = m0 >> 12, nb = (m0 & 4095) + w * 32;
        #pragma unroll
        for (int fr = 0; fr < 2; fr++)
            #pragma unroll
            for (int fn = 0; fn < 4; fn++) {
                int o = n0 + fn * 16 + l15;
                int n = nb + fr * 16 + quad * 4;
                u16x4 pk;
                #pragma unroll
                for (int r = 0; r < 4; r++) pk[r] = f2bf(acc[fr][fn][r]);
                *(u16x4*)(&out[(((size_t)(b * 256 + o)) << 12) + n]) = pk;
            }
    } else {
        float* out = (float*)outp;
        float gm = gamma[0];
        int b = m0 >> 12, nb = (m0 & 4095) + w * 32;
        #pragma unroll
        for (int fr = 0; fr < 2; fr++)
            #pragma unroll
            for (int fn = 0; fn < 4; fn++) {
                int o = n0 + fn * 16 + l15;
                int n = nb + fr * 16 + quad * 4;
                size_t base = (((size_t)(b * 256 + o)) << 12) + n;
                f32x4 xv = *(const f32x4*)(xres + base);
                f32x4 ov;
                #pragma unroll
                for (int r = 0; r < 4; r++) ov[r] = xv[r] + gm * acc[fr][fn][r];
                *(f32x4*)(out + base) = ov;
            }
    }
}

// ---------------- flash attention, fixed-max softmax ----------------
// QK: (B*N, 64) bf16 (q cols 0..31 pre-scaled by log2e/sqrt(d), k cols 32..63).
// Vt: (B, 256, N) bf16.  Block: 64 q-rows, 4 waves x 16 rows. Bc=64, 64 tiles.
// P = exp2(S - 12) with S already in exp2 domain; softmax scale-invariance
// makes the fixed max exact. l via ones-MFMA. No rescaling anywhere.
__global__ __launch_bounds__(256) void k_flash(
        const unsigned short* __restrict__ QK, const unsigned short* __restrict__ Vt,
        unsigned short* __restrict__ Oa) {
    int id = blockIdx.x;
    int b = id & 7, qt = id >> 3;      // batch <-> XCD affinity
    int t = threadIdx.x, w = t >> 6, lane = t & 63, l15 = lane & 15, quad = lane >> 4;
    int ln = lane;
    __shared__ unsigned short lK[64 * 32];        // 64 keys x 32 dd (unpadded: glds)
    __shared__ unsigned short lV[256 * 64];       // 256 o x 64 keys (unpadded: glds)
    __shared__ unsigned short lP[4][16 * 88];     // per-wave P, pad 64->88
    int q0 = qt * 64;
    bf16x8 qf = *(const bf16x8*)(QK + ((size_t)(b * 4096 + q0 + w * 16 + l15)) * 64 + quad * 8);
    u16x8 onesu = {0x3F80, 0x3F80, 0x3F80, 0x3F80, 0x3F80, 0x3F80, 0x3F80, 0x3F80};
    bf16x8 ones = __builtin_bit_cast(bf16x8, onesu);
    f32x4 z4 = {0.f, 0.f, 0.f, 0.f};
    f32x4 minit = {-MFIX, -MFIX, -MFIX, -MFIX};
    f32x4 O[16];
    #pragma unroll
    for (int i = 0; i < 16; i++) O[i] = z4;
    f32x4 lacc = z4;

    // staging addresses (per-lane global, wave-uniform LDS)
    const unsigned short* gK = QK + ((size_t)(b * 4096 + w * 16 + (ln >> 2))) * 64 + 32 + (ln & 3) * 8;
    unsigned short* sK = lK + w * 512;                 // + ln*8 implicit (lane*16B)
    const unsigned short* gV = Vt + (((size_t)(b * 256 + w * 64 + (ln >> 3))) << 12) + (ln & 7) * 8;
    unsigned short* sV = lV + w * 4096;

    for (int kt = 0; kt < 64; kt++) {
        glds16(gK + (size_t)kt * 64 * 64, sK);
        #pragma unroll
        for (int j = 0; j < 8; j++)
            glds16(gV + ((size_t)j * 8 << 12) + kt * 64, sV + j * 512);
        __syncthreads();

        // S = q.K^T - M  (C-init carries -M; Wq carries scale*log2e)
        f32x4 S[4];
        #pragma unroll
        for (int f = 0; f < 4; f++) {
            bf16x8 kf = *(const bf16x8*)(&lK[(f * 16 + l15) * 32 + quad * 8]);
            S[f] = mfma16(qf, kf, minit);
        }
        // P = exp2(S), D-layout -> LDS (per-wave region, in-order DS)
        #pragma unroll
        for (int f = 0; f < 4; f++)
            #pragma unroll
            for (int r = 0; r < 4; r++)
                lP[w][(quad * 4 + r) * 88 + f * 16 + l15] =
                    f2bf(__builtin_amdgcn_exp2f(S[f][r]));

        #pragma unroll
        for (int ks = 0; ks < 2; ks++) {
            bf16x8 pa = *(const bf16x8*)(&lP[w][l15 * 88 + ks * 32 + quad * 8]);
            lacc = mfma16(pa, ones, lacc);         // rowsum via ones-MFMA
            #pragma unroll
            for (int c = 0; c < 16; c++) {
                bf16x8 vf = *(const bf16x8*)(&lV[(c * 16 + l15) * 64 + ks * 32 + quad * 8]);
                O[c] = mfma16(pa, vf, O[c]);
            }
        }
        __syncthreads();   // protect lK/lV before next stage
    }

    float rl[4];
    #pragma unroll
    for (int r = 0; r < 4; r++) rl[r] = 1.f / lacc[r];
    #pragma unroll
    for (int c = 0; c < 16; c++)
        #pragma unroll
        for (int r = 0; r < 4; r++) {
            size_t row = (size_t)(b * 4096 + q0 + w * 16 + quad * 4 + r);
            Oa[row * 256 + c * 16 + l15] = f2bf(O[c][r] * rl[r]);
        }
}

// ---------------- launch ----------------
extern "C" void kernel_launch(void* const* d_in, const int* in_sizes, int n_in,
                              void* d_out, int out_size, void* d_ws, size_t ws_size,
                              hipStream_t stream) {
    const float* x  = (const float*)d_in[0];
    const float* nw = (const float*)d_in[1];
    const float* nb = (const float*)d_in[2];
    const float* wq = (const float*)d_in[3];
    const float* wk = (const float*)d_in[4];
    const float* wv = (const float*)d_in[5];
    const float* wp = (const float*)d_in[6];
    const float* gm = (const float*)d_in[7];

    char* p = (char*)d_ws;
    unsigned short* ht  = (unsigned short*)p; p += (size_t)32768 * 256 * 2;  // 16 MB
    unsigned short* qk  = (unsigned short*)p; p += (size_t)32768 * 64 * 2;   // 4 MB
    unsigned short* vt  = (unsigned short*)p; p += (size_t)8 * 256 * 4096 * 2; // 16 MB
    unsigned short* oa  = (unsigned short*)p; p += (size_t)32768 * 256 * 2;  // 16 MB
    unsigned short* bqk = (unsigned short*)p; p += 64 * 256 * 2;
    unsigned short* bv  = (unsigned short*)p; p += 256 * 256 * 2;
    unsigned short* bp  = (unsigned short*)p; p += 256 * 256 * 2;

    k_pack<<<dim3(256), dim3(256), 0, stream>>>(wq, wk, wv, wp, bqk, bv, bp);
    k_gnorm<<<dim3(256), dim3(256), 0, stream>>>(x, nw, nb, ht);
    k_gemm<0><<<dim3(256, 1), dim3(256), 0, stream>>>(ht, bqk, (void*)qk, nullptr, nullptr, 64);
    k_gemm<1><<<dim3(256, 4), dim3(256), 0, stream>>>(ht, bv, (void*)vt, nullptr, nullptr, 0);
    k_flash<<<dim3(512), dim3(256), 0, stream>>>(qk, vt, oa);
    k_gemm<2><<<dim3(256, 4), dim3(256), 0, stream>>>(oa, bp, d_out, x, gm, 0);
}

// Round 3
// 262.998 us; speedup vs baseline: 1.5416x; 1.4821x over previous
//
#include <hip/hip_runtime.h>
#include <cstdint>

// Shapes: B=8, C=256, H=W=64 -> N=4096, d=32, groups=32 (8 ch/group)

typedef __bf16 bf16x8 __attribute__((ext_vector_type(8)));
typedef float f32x4 __attribute__((ext_vector_type(4)));
typedef unsigned int u32x4 __attribute__((ext_vector_type(4)));
typedef unsigned short u16x4 __attribute__((ext_vector_type(4)));
typedef unsigned short u16x8 __attribute__((ext_vector_type(8)));

#define DEVI __device__ __forceinline__

DEVI unsigned short f2bf(float f) {
    __bf16 h = (__bf16)f;               // RNE fptrunc
    return __builtin_bit_cast(unsigned short, h);
}

DEVI f32x4 mfma16(bf16x8 a, bf16x8 b, f32x4 c) {
    return __builtin_amdgcn_mfma_f32_16x16x32_bf16(a, b, c, 0, 0, 0);
}

// async global->LDS, 16B per lane, wave-uniform LDS base + lane*16
DEVI void glds16(const unsigned short* g, unsigned short* l) {
    const __attribute__((address_space(1))) unsigned int* gp =
        reinterpret_cast<const __attribute__((address_space(1))) unsigned int*>(
            reinterpret_cast<uintptr_t>(g));
    __attribute__((address_space(3))) unsigned int* lp =
        reinterpret_cast<__attribute__((address_space(3))) unsigned int*>(
            reinterpret_cast<uintptr_t>(l));
    __builtin_amdgcn_global_load_lds(gp, lp, 16, 0, 0);
}

// log2(e)/sqrt(32): folded into Wq so S exits QK-MFMA in exp2 domain
#define QSCALE 0.2550663133f
#define MFIX   12.0f

// ---------------- weight pack fp32 -> bf16 ----------------
__global__ __launch_bounds__(256) void k_pack(
        const float* __restrict__ wq, const float* __restrict__ wk,
        const float* __restrict__ wv, const float* __restrict__ wp,
        unsigned short* __restrict__ bqk, unsigned short* __restrict__ bv,
        unsigned short* __restrict__ bp) {
    int i = blockIdx.x * 256 + threadIdx.x;        // grid 256 -> 65536 threads
    if (i < 8192)       bqk[i] = f2bf(wq[i] * QSCALE);   // rows 0..31 = Wq (pre-scaled)
    else if (i < 16384) bqk[i] = f2bf(wk[i - 8192]);     // rows 32..63 = Wk
    bv[i] = f2bf(wv[i]);
    bp[i] = f2bf(wp[i]);
}

// ---------------- group norm -> h^T (B*N, C) bf16 ----------------
// 256 blocks (one per batch x group), 1024 threads, f32x4 loads both passes.
__global__ __launch_bounds__(1024) void k_gnorm(
        const float* __restrict__ x, const float* __restrict__ gw,
        const float* __restrict__ gb, unsigned short* __restrict__ ht) {
    int bg = blockIdx.x;               // 256 blocks = 8 batches * 32 groups
    int b = bg >> 5, g = bg & 31;
    const float* xb = x + ((size_t)(b * 256 + g * 8)) * 4096;  // 8 contiguous rows
    int t = threadIdx.x;
    float s1 = 0.f, s2 = 0.f;
    const f32x4* xv4 = (const f32x4*)xb;
    for (int i = t; i < 8192; i += 1024) {       // 32768 floats = 8192 f32x4
        f32x4 v = xv4[i];
        #pragma unroll
        for (int j = 0; j < 4; j++) { s1 += v[j]; s2 += v[j] * v[j]; }
    }
    #pragma unroll
    for (int off = 1; off < 64; off <<= 1) {
        s1 += __shfl_xor(s1, off);
        s2 += __shfl_xor(s2, off);
    }
    __shared__ float red[34];
    int wv_ = t >> 6;                            // 16 waves
    if ((t & 63) == 0) { red[wv_ * 2] = s1; red[wv_ * 2 + 1] = s2; }
    __syncthreads();
    if (t == 0) {
        float a = 0.f, q = 0.f;
        #pragma unroll
        for (int i = 0; i < 16; i++) { a += red[i * 2]; q += red[i * 2 + 1]; }
        float mean = a * (1.f / 32768.f);
        float var = q * (1.f / 32768.f) - mean * mean;
        red[32] = mean; red[33] = rsqrtf(var + 1e-5f);
    }
    __syncthreads();
    float mean = red[32], rstd = red[33];
    float wv8[8], bv8[8];
    #pragma unroll
    for (int c = 0; c < 8; c++) { wv8[c] = gw[g * 8 + c] * rstd; bv8[c] = gb[g * 8 + c] - mean * rstd * gw[g * 8 + c]; }
    // pass 2: thread t handles n = t*4 .. t*4+3 (4096 n / 1024 threads)
    int n0 = t * 4;
    f32x4 cv[8];
    #pragma unroll
    for (int c = 0; c < 8; c++) cv[c] = *(const f32x4*)(xb + c * 4096 + n0);
    #pragma unroll
    for (int j = 0; j < 4; j++) {
        u16x8 pk;
        #pragma unroll
        for (int c = 0; c < 8; c++) pk[c] = f2bf(cv[c][j] * wv8[c] + bv8[c]);
        *(u16x8*)(&ht[((size_t)(b * 4096 + n0 + j)) * 256 + g * 8]) = pk;  // 16B store
    }
}

// ---------------- GEMM  C[M x Ncols] = A[M x 256] * Bw[Ncols x 256]^T ----------------
// BM=128, BN=64, BK=64. 4 waves; wave w: rows [w*32, w*32+32) x 64 cols.
// EPI 0: bf16 row-major out (ldout).  EPI 1: bf16 transposed (Vt[b][o][n]).
// EPI 2: fp32 transposed + residual: out[b][o][n] = x + gamma*acc.
template <int EPI>
__global__ __launch_bounds__(256) void k_gemm(
        const unsigned short* __restrict__ A, const unsigned short* __restrict__ Bw,
        void* __restrict__ outp, const float* __restrict__ xres,
        const float* __restrict__ gamma, int ldout) {
    __shared__ unsigned short lA[128 * 72];   // rows padded 64->72 elems
    __shared__ unsigned short lB[64 * 72];
    int t = threadIdx.x;
    int m0 = blockIdx.x * 128, n0 = blockIdx.y * 64;
    int w = t >> 6, lane = t & 63, l15 = lane & 15, quad = lane >> 4;
    f32x4 z4 = {0.f, 0.f, 0.f, 0.f};
    f32x4 acc[2][4];
    #pragma unroll
    for (int i = 0; i < 2; i++)
        #pragma unroll
        for (int j = 0; j < 4; j++) acc[i][j] = z4;

    for (int kb = 0; kb < 4; kb++) {
        #pragma unroll
        for (int i = 0; i < 4; i++) {
            int ch = i * 256 + t;
            int row = ch >> 3, col = (ch & 7) * 8;
            u32x4 v = *(const u32x4*)(A + (size_t)(m0 + row) * 256 + kb * 64 + col);
            *(u32x4*)(&lA[row * 72 + col]) = v;
        }
        #pragma unroll
        for (int i = 0; i < 2; i++) {
            int ch = i * 256 + t;
            int row = ch >> 3, col = (ch & 7) * 8;
            u32x4 v = *(const u32x4*)(Bw + (size_t)(n0 + row) * 256 + kb * 64 + col);
            *(u32x4*)(&lB[row * 72 + col]) = v;
        }
        __syncthreads();
        #pragma unroll
        for (int ks = 0; ks < 2; ks++) {
            bf16x8 af[2], bfr[4];
            #pragma unroll
            for (int fr = 0; fr < 2; fr++)
                af[fr] = *(const bf16x8*)(&lA[(w * 32 + fr * 16 + l15) * 72 + ks * 32 + quad * 8]);
            #pragma unroll
            for (int fn = 0; fn < 4; fn++)
                bfr[fn] = *(const bf16x8*)(&lB[(fn * 16 + l15) * 72 + ks * 32 + quad * 8]);
            #pragma unroll
            for (int fr = 0; fr < 2; fr++)
                #pragma unroll
                for (int fn = 0; fn < 4; fn++)
                    acc[fr][fn] = mfma16(af[fr], bfr[fn], acc[fr][fn]);
        }
        __syncthreads();
    }

    if (EPI == 0) {
        unsigned short* out = (unsigned short*)outp;
        #pragma unroll
        for (int fr = 0; fr < 2; fr++)
            #pragma unroll
            for (int fn = 0; fn < 4; fn++)
                #pragma unroll
                for (int r = 0; r < 4; r++) {
                    int m = m0 + w * 32 + fr * 16 + quad * 4 + r;
                    int n = n0 + fn * 16 + l15;
                    out[(size_t)m * ldout + n] = f2bf(acc[fr][fn][r]);
                }
    } else if (EPI == 1) {
        unsigned short* out = (unsigned short*)outp;
        int b = m0 >> 12, nb = (m0 & 4095) + w * 32;
        #pragma unroll
        for (int fr = 0; fr < 2; fr++)
            #pragma unroll
            for (int fn = 0; fn < 4; fn++) {
                int o = n0 + fn * 16 + l15;
                int n = nb + fr * 16 + quad * 4;
                u16x4 pk;
                #pragma unroll
                for (int r = 0; r < 4; r++) pk[r] = f2bf(acc[fr][fn][r]);
                *(u16x4*)(&out[(((size_t)(b * 256 + o)) << 12) + n]) = pk;
            }
    } else {
        float* out = (float*)outp;
        float gm = gamma[0];
        int b = m0 >> 12, nb = (m0 & 4095) + w * 32;
        #pragma unroll
        for (int fr = 0; fr < 2; fr++)
            #pragma unroll
            for (int fn = 0; fn < 4; fn++) {
                int o = n0 + fn * 16 + l15;
                int n = nb + fr * 16 + quad * 4;
                size_t base = (((size_t)(b * 256 + o)) << 12) + n;
                f32x4 xv = *(const f32x4*)(xres + base);
                f32x4 ov;
                #pragma unroll
                for (int r = 0; r < 4; r++) ov[r] = xv[r] + gm * acc[fr][fn][r];
                *(f32x4*)(out + base) = ov;
            }
    }
}

// ---------------- flash attention, fixed-max softmax, XOR-swizzled V ----------------
// QK: (B*N, 64) bf16 (q cols 0..31 pre-scaled by log2e/sqrt(d), k cols 32..63).
// Vt: (B, 256, N) bf16.  Block: 64 q-rows, 4 waves x 16 rows. Bc=64, 64 tiles.
// lV layout: slot s of row o holds global chunk (s ^ (o&7)) -> conflict-free
// b128 reads despite glds-forced unpadded rows. lK needs no swizzle
// (bank group = (l15&1)*4+quad, already uniform).
__global__ __launch_bounds__(256) void k_flash(
        const unsigned short* __restrict__ QK, const unsigned short* __restrict__ Vt,
        unsigned short* __restrict__ Oa) {
    int id = blockIdx.x;
    int b = id & 7, qt = id >> 3;      // batch <-> XCD affinity
    int t = threadIdx.x, w = t >> 6, lane = t & 63, l15 = lane & 15, quad = lane >> 4;
    int ln = lane;
    __shared__ unsigned short lK[64 * 32];        // 64 keys x 32 dd
    __shared__ unsigned short lV[256 * 64];       // 256 o x 64 keys (swizzled)
    __shared__ unsigned short lP[4][16 * 88];     // per-wave P, pad 64->88
    int q0 = qt * 64;
    bf16x8 qf = *(const bf16x8*)(QK + ((size_t)(b * 4096 + q0 + w * 16 + l15)) * 64 + quad * 8);
    u16x8 onesu = {0x3F80, 0x3F80, 0x3F80, 0x3F80, 0x3F80, 0x3F80, 0x3F80, 0x3F80};
    bf16x8 ones = __builtin_bit_cast(bf16x8, onesu);
    f32x4 z4 = {0.f, 0.f, 0.f, 0.f};
    f32x4 minit = {-MFIX, -MFIX, -MFIX, -MFIX};
    f32x4 O[16];
    #pragma unroll
    for (int i = 0; i < 16; i++) O[i] = z4;
    f32x4 lacc = z4;

    // staging addresses (per-lane global, wave-uniform LDS)
    const unsigned short* gK = QK + ((size_t)(b * 4096 + w * 16 + (ln >> 2))) * 64 + 32 + (ln & 3) * 8;
    unsigned short* sK = lK + w * 512;                 // + ln*8 implicit (lane*16B)
    // V: lane ln, issue j -> row o = w*64 + j*8 + (ln>>3), slot s = ln&7.
    // swizzle: fetch global chunk c8 = s ^ (o&7) = (ln&7) ^ ((ln>>3)&7)
    int vc8 = (ln & 7) ^ ((ln >> 3) & 7);
    const unsigned short* gV = Vt + (((size_t)(b * 256 + w * 64 + (ln >> 3))) << 12) + vc8 * 8;
    unsigned short* sV = lV + w * 4096;

    for (int kt = 0; kt < 64; kt++) {
        glds16(gK + (size_t)kt * 64 * 64, sK);
        #pragma unroll
        for (int j = 0; j < 8; j++)
            glds16(gV + ((size_t)j * 8 << 12) + kt * 64, sV + j * 512);
        __syncthreads();

        // S = q.K^T - M  (C-init carries -M; Wq carries scale*log2e)
        f32x4 S[4];
        #pragma unroll
        for (int f = 0; f < 4; f++) {
            bf16x8 kf = *(const bf16x8*)(&lK[(f * 16 + l15) * 32 + quad * 8]);
            S[f] = mfma16(qf, kf, minit);
        }
        // P = exp2(S), D-layout -> LDS (per-wave region, in-order DS)
        #pragma unroll
        for (int f = 0; f < 4; f++)
            #pragma unroll
            for (int r = 0; r < 4; r++)
                lP[w][(quad * 4 + r) * 88 + f * 16 + l15] =
                    f2bf(__builtin_amdgcn_exp2f(S[f][r]));

        #pragma unroll
        for (int ks = 0; ks < 2; ks++) {
            bf16x8 pa = *(const bf16x8*)(&lP[w][l15 * 88 + ks * 32 + quad * 8]);
            lacc = mfma16(pa, ones, lacc);         // rowsum via ones-MFMA
            int sl = ((ks * 4 + quad) ^ (l15 & 7)) * 8;   // V swizzle slot
            #pragma unroll
            for (int c = 0; c < 16; c++) {
                bf16x8 vf = *(const bf16x8*)(&lV[(c * 16 + l15) * 64 + sl]);
                O[c] = mfma16(pa, vf, O[c]);
            }
        }
        __syncthreads();   // protect lK/lV before next stage
    }

    float rl[4];
    #pragma unroll
    for (int r = 0; r < 4; r++) rl[r] = 1.f / lacc[r];
    #pragma unroll
    for (int c = 0; c < 16; c++)
        #pragma unroll
        for (int r = 0; r < 4; r++) {
            size_t row = (size_t)(b * 4096 + q0 + w * 16 + quad * 4 + r);
            Oa[row * 256 + c * 16 + l15] = f2bf(O[c][r] * rl[r]);
        }
}

// ---------------- launch ----------------
extern "C" void kernel_launch(void* const* d_in, const int* in_sizes, int n_in,
                              void* d_out, int out_size, void* d_ws, size_t ws_size,
                              hipStream_t stream) {
    const float* x  = (const float*)d_in[0];
    const float* nw = (const float*)d_in[1];
    const float* nb = (const float*)d_in[2];
    const float* wq = (const float*)d_in[3];
    const float* wk = (const float*)d_in[4];
    const float* wv = (const float*)d_in[5];
    const float* wp = (const float*)d_in[6];
    const float* gm = (const float*)d_in[7];

    char* p = (char*)d_ws;
    unsigned short* ht  = (unsigned short*)p; p += (size_t)32768 * 256 * 2;  // 16 MB
    unsigned short* qk  = (unsigned short*)p; p += (size_t)32768 * 64 * 2;   // 4 MB
    unsigned short* vt  = (unsigned short*)p; p += (size_t)8 * 256 * 4096 * 2; // 16 MB
    unsigned short* oa  = (unsigned short*)p; p += (size_t)32768 * 256 * 2;  // 16 MB
    unsigned short* bqk = (unsigned short*)p; p += 64 * 256 * 2;
    unsigned short* bv  = (unsigned short*)p; p += 256 * 256 * 2;
    unsigned short* bp  = (unsigned short*)p; p += 256 * 256 * 2;

    k_pack<<<dim3(256), dim3(256), 0, stream>>>(wq, wk, wv, wp, bqk, bv, bp);
    k_gnorm<<<dim3(256), dim3(1024), 0, stream>>>(x, nw, nb, ht);
    k_gemm<0><<<dim3(256, 1), dim3(256), 0, stream>>>(ht, bqk, (void*)qk, nullptr, nullptr, 64);
    k_gemm<1><<<dim3(256, 4), dim3(256), 0, stream>>>(ht, bv, (void*)vt, nullptr, nullptr, 0);
    k_flash<<<dim3(512), dim3(256), 0, stream>>>(qk, vt, oa);
    k_gemm<2><<<dim3(256, 4), dim3(256), 0, stream>>>(oa, bp, d_out, x, gm, 0);
}

// Round 4
// 236.145 us; speedup vs baseline: 1.7170x; 1.1137x over previous
//
#include <hip/hip_runtime.h>
#include <cstdint>

// Shapes: B=8, C=256, H=W=64 -> N=4096, d=32, groups=32 (8 ch/group)

typedef __bf16 bf16x8 __attribute__((ext_vector_type(8)));
typedef float f32x4 __attribute__((ext_vector_type(4)));
typedef float f32x16 __attribute__((ext_vector_type(16)));
typedef unsigned int u32x4 __attribute__((ext_vector_type(4)));
typedef unsigned short u16x4 __attribute__((ext_vector_type(4)));
typedef unsigned short u16x8 __attribute__((ext_vector_type(8)));

#define DEVI __device__ __forceinline__

DEVI unsigned short f2bf(float f) {
    __bf16 h = (__bf16)f;               // RNE fptrunc
    return __builtin_bit_cast(unsigned short, h);
}
DEVI float bf2f(unsigned short u) {
    unsigned int x = ((unsigned int)u) << 16;
    return __builtin_bit_cast(float, x);
}

DEVI f32x4 mfma16(bf16x8 a, bf16x8 b, f32x4 c) {
    return __builtin_amdgcn_mfma_f32_16x16x32_bf16(a, b, c, 0, 0, 0);
}
DEVI f32x16 mfma32(bf16x8 a, bf16x8 b, f32x16 c) {
    return __builtin_amdgcn_mfma_f32_32x32x16_bf16(a, b, c, 0, 0, 0);
}

// async global->LDS, 16B per lane, wave-uniform LDS base + lane*16
DEVI void glds16(const unsigned short* g, unsigned short* l) {
    const __attribute__((address_space(1))) unsigned int* gp =
        reinterpret_cast<const __attribute__((address_space(1))) unsigned int*>(
            reinterpret_cast<uintptr_t>(g));
    __attribute__((address_space(3))) unsigned int* lp =
        reinterpret_cast<__attribute__((address_space(3))) unsigned int*>(
            reinterpret_cast<uintptr_t>(l));
    __builtin_amdgcn_global_load_lds(gp, lp, 16, 0, 0);
}

// log2(e)/sqrt(32): folded into Wq so S exits QK-MFMA in exp2 domain
#define QSCALE 0.2550663133f
#define MFIX   12.0f

// ---------------- weight pack fp32 -> bf16 ----------------
__global__ __launch_bounds__(256) void k_pack(
        const float* __restrict__ wq, const float* __restrict__ wk,
        const float* __restrict__ wv, const float* __restrict__ wp,
        unsigned short* __restrict__ bqk, unsigned short* __restrict__ bv,
        unsigned short* __restrict__ bp) {
    int i = blockIdx.x * 256 + threadIdx.x;        // grid 256 -> 65536 threads
    if (i < 8192)       bqk[i] = f2bf(wq[i] * QSCALE);   // rows 0..31 = Wq (pre-scaled)
    else if (i < 16384) bqk[i] = f2bf(wk[i - 8192]);     // rows 32..63 = Wk
    bv[i] = f2bf(wv[i]);
    bp[i] = f2bf(wp[i]);
}

// ---------------- group norm -> h^T (B*N, C) bf16 ----------------
__global__ __launch_bounds__(1024) void k_gnorm(
        const float* __restrict__ x, const float* __restrict__ gw,
        const float* __restrict__ gb, unsigned short* __restrict__ ht) {
    int bg = blockIdx.x;               // 256 blocks = 8 batches * 32 groups
    int b = bg >> 5, g = bg & 31;
    const float* xb = x + ((size_t)(b * 256 + g * 8)) * 4096;  // 8 contiguous rows
    int t = threadIdx.x;
    float s1 = 0.f, s2 = 0.f;
    const f32x4* xv4 = (const f32x4*)xb;
    for (int i = t; i < 8192; i += 1024) {
        f32x4 v = xv4[i];
        #pragma unroll
        for (int j = 0; j < 4; j++) { s1 += v[j]; s2 += v[j] * v[j]; }
    }
    #pragma unroll
    for (int off = 1; off < 64; off <<= 1) {
        s1 += __shfl_xor(s1, off);
        s2 += __shfl_xor(s2, off);
    }
    __shared__ float red[34];
    int wv_ = t >> 6;
    if ((t & 63) == 0) { red[wv_ * 2] = s1; red[wv_ * 2 + 1] = s2; }
    __syncthreads();
    if (t == 0) {
        float a = 0.f, q = 0.f;
        #pragma unroll
        for (int i = 0; i < 16; i++) { a += red[i * 2]; q += red[i * 2 + 1]; }
        float mean = a * (1.f / 32768.f);
        float var = q * (1.f / 32768.f) - mean * mean;
        red[32] = mean; red[33] = rsqrtf(var + 1e-5f);
    }
    __syncthreads();
    float mean = red[32], rstd = red[33];
    float wv8[8], bv8[8];
    #pragma unroll
    for (int c = 0; c < 8; c++) { wv8[c] = gw[g * 8 + c] * rstd; bv8[c] = gb[g * 8 + c] - mean * rstd * gw[g * 8 + c]; }
    int n0 = t * 4;
    f32x4 cv[8];
    #pragma unroll
    for (int c = 0; c < 8; c++) cv[c] = *(const f32x4*)(xb + c * 4096 + n0);
    #pragma unroll
    for (int j = 0; j < 4; j++) {
        u16x8 pk;
        #pragma unroll
        for (int c = 0; c < 8; c++) pk[c] = f2bf(cv[c][j] * wv8[c] + bv8[c]);
        *(u16x8*)(&ht[((size_t)(b * 4096 + n0 + j)) * 256 + g * 8]) = pk;  // 16B store
    }
}

// ---------------- GEMM  C[M x Ncols] = A[M x 256] * Bw[Ncols x 256]^T ----------------
// EPI 0: bf16 row-major out (ldout).  EPI 1: bf16 transposed Vt[b][o][n] with
//        key-dim bit2<->bit3 swap per 16-group (PV A-frag permutation).
// EPI 2: fp32 transposed + residual: out[b][o][n] = x + gamma*acc.
template <int EPI>
__global__ __launch_bounds__(256) void k_gemm(
        const unsigned short* __restrict__ A, const unsigned short* __restrict__ Bw,
        void* __restrict__ outp, const float* __restrict__ xres,
        const float* __restrict__ gamma, int ldout) {
    __shared__ unsigned short lA[128 * 72];
    __shared__ unsigned short lB[64 * 72];
    int t = threadIdx.x;
    int m0 = blockIdx.x * 128, n0 = blockIdx.y * 64;
    int w = t >> 6, lane = t & 63, l15 = lane & 15, quad = lane >> 4;
    f32x4 z4 = {0.f, 0.f, 0.f, 0.f};
    f32x4 acc[2][4];
    #pragma unroll
    for (int i = 0; i < 2; i++)
        #pragma unroll
        for (int j = 0; j < 4; j++) acc[i][j] = z4;

    for (int kb = 0; kb < 4; kb++) {
        #pragma unroll
        for (int i = 0; i < 4; i++) {
            int ch = i * 256 + t;
            int row = ch >> 3, col = (ch & 7) * 8;
            u32x4 v = *(const u32x4*)(A + (size_t)(m0 + row) * 256 + kb * 64 + col);
            *(u32x4*)(&lA[row * 72 + col]) = v;
        }
        #pragma unroll
        for (int i = 0; i < 2; i++) {
            int ch = i * 256 + t;
            int row = ch >> 3, col = (ch & 7) * 8;
            u32x4 v = *(const u32x4*)(Bw + (size_t)(n0 + row) * 256 + kb * 64 + col);
            *(u32x4*)(&lB[row * 72 + col]) = v;
        }
        __syncthreads();
        #pragma unroll
        for (int ks = 0; ks < 2; ks++) {
            bf16x8 af[2], bfr[4];
            #pragma unroll
            for (int fr = 0; fr < 2; fr++)
                af[fr] = *(const bf16x8*)(&lA[(w * 32 + fr * 16 + l15) * 72 + ks * 32 + quad * 8]);
            #pragma unroll
            for (int fn = 0; fn < 4; fn++)
                bfr[fn] = *(const bf16x8*)(&lB[(fn * 16 + l15) * 72 + ks * 32 + quad * 8]);
            #pragma unroll
            for (int fr = 0; fr < 2; fr++)
                #pragma unroll
                for (int fn = 0; fn < 4; fn++)
                    acc[fr][fn] = mfma16(af[fr], bfr[fn], acc[fr][fn]);
        }
        __syncthreads();
    }

    if (EPI == 0) {
        unsigned short* out = (unsigned short*)outp;
        #pragma unroll
        for (int fr = 0; fr < 2; fr++)
            #pragma unroll
            for (int fn = 0; fn < 4; fn++)
                #pragma unroll
                for (int r = 0; r < 4; r++) {
                    int m = m0 + w * 32 + fr * 16 + quad * 4 + r;
                    int n = n0 + fn * 16 + l15;
                    out[(size_t)m * ldout + n] = f2bf(acc[fr][fn][r]);
                }
    } else if (EPI == 1) {
        unsigned short* out = (unsigned short*)outp;
        int b = m0 >> 12, nb = (m0 & 4095) + w * 32;
        int swq = ((quad & 1) << 1) | (quad >> 1);   // bit2<->bit3 swap of n within 16
        #pragma unroll
        for (int fr = 0; fr < 2; fr++)
            #pragma unroll
            for (int fn = 0; fn < 4; fn++) {
                int o = n0 + fn * 16 + l15;
                int n = nb + fr * 16 + swq * 4;
                u16x4 pk;
                #pragma unroll
                for (int r = 0; r < 4; r++) pk[r] = f2bf(acc[fr][fn][r]);
                *(u16x4*)(&out[(((size_t)(b * 256 + o)) << 12) + n]) = pk;
            }
    } else {
        float* out = (float*)outp;
        float gm = gamma[0];
        int b = m0 >> 12, nb = (m0 & 4095) + w * 32;
        #pragma unroll
        for (int fr = 0; fr < 2; fr++)
            #pragma unroll
            for (int fn = 0; fn < 4; fn++) {
                int o = n0 + fn * 16 + l15;
                int n = nb + fr * 16 + quad * 4;
                size_t base = (((size_t)(b * 256 + o)) << 12) + n;
                f32x4 xv = *(const f32x4*)(xres + base);
                f32x4 ov;
                #pragma unroll
                for (int r = 0; r < 4; r++) ov[r] = xv[r] + gm * acc[fr][fn][r];
                *(f32x4*)(out + base) = ov;
            }
    }
}

// ---------------- flash attention: 32x32 MFMA, St-in-register, no P round-trip ----
// QK: (B*N, 64) bf16 (q cols 0..31 pre-scaled, k cols 32..63).
// Vt: (B, 256, N) bf16, key-dim sigma-permuted (bit2<->bit3 per 16-group).
// Block: 64 q-rows, 4 waves = 2 q-halves x 2 key-halves; Bc=64, 64 tiles.
// St = K.Q^T via 32x32x16: D(col=lane&31=q, row=key) == PV A-frag layout
// (m=lane&31=q, k permuted) -> P stays in registers. Cross-wave (key-half)
// O/l combine through LDS once at the end.
__global__ __launch_bounds__(256, 2) void k_flash(
        const unsigned short* __restrict__ QK, const unsigned short* __restrict__ Vt,
        unsigned short* __restrict__ Oa) {
    __shared__ __align__(16) char smem[40960];
    unsigned short* lK = (unsigned short*)smem;          // 64 keys x 32 d (chunk-swizzled)
    unsigned short* lV = (unsigned short*)(smem + 4096); // 256 o x 64 pos (chunk-swizzled)
    int id = blockIdx.x;
    int b = id & 7, qt = id >> 3;      // batch <-> XCD affinity
    int t = threadIdx.x, w = t >> 6, ln = t & 63;
    int l31 = ln & 31, h = ln >> 5;
    int qh = w >> 1, kh = w & 1;
    int q0 = qt * 64;

    // persistent Q B-frag: B[k=d][n=q]; lane: q=l31, d = s*16 + h*8 + j (contiguous 16B)
    const unsigned short* qrow = QK + ((size_t)(b * 4096 + q0 + qh * 32 + l31)) * 64;
    bf16x8 qb0 = *(const bf16x8*)(qrow + h * 8);
    bf16x8 qb1 = *(const bf16x8*)(qrow + 16 + h * 8);

    // staging: K tile (wave w stages keys w*16..+16), chunk-swizzled for A-frag reads
    int cgK = (ln & 3) ^ ((ln >> 2) & 3) ^ ((ln >> 4) & 3);
    const unsigned short* gK = QK + ((size_t)(b * 4096 + w * 16 + (ln >> 2))) * 64 + 32 + cgK * 8;
    unsigned short* sK = lK + w * 512;
    // V tile: wave w stages o-rows w*64..+64, chunk-swizzled (slot = chunk ^ (o&7))
    int vc8 = (ln & 7) ^ ((ln >> 3) & 7);
    const unsigned short* gV = Vt + (((size_t)(b * 256 + w * 64 + (ln >> 3))) << 12) + vc8 * 8;
    unsigned short* sV = lV + w * 4096;

    u16x8 onesu = {0x3F80, 0x3F80, 0x3F80, 0x3F80, 0x3F80, 0x3F80, 0x3F80, 0x3F80};
    bf16x8 ones = __builtin_bit_cast(bf16x8, onesu);
    f32x16 z16;
    #pragma unroll
    for (int i = 0; i < 16; i++) z16[i] = 0.f;
    f32x16 minit;
    #pragma unroll
    for (int i = 0; i < 16; i++) minit[i] = -MFIX;
    f32x16 Oacc[8];
    #pragma unroll
    for (int i = 0; i < 8; i++) Oacc[i] = z16;
    f32x16 lacc = z16;

    // loop-invariant LDS read offsets
    int gl = (ln & 3) ^ ((ln >> 2) & 3);
    const unsigned short* kf0p = lK + (kh * 32 + l31) * 32 + ((0 + h) ^ gl) * 8;
    const unsigned short* kf1p = lK + (kh * 32 + l31) * 32 + ((2 + h) ^ gl) * 8;

    for (int kt = 0; kt < 64; kt++) {
        glds16(gK + (size_t)kt * 4096, sK);
        #pragma unroll
        for (int j = 0; j < 8; j++)
            glds16(gV + ((size_t)j * 8 << 12) + kt * 64, sV + j * 512);
        __syncthreads();

        // St = K.Q^T - M (32x32, K-dim d=32 in two steps)
        bf16x8 kf0 = *(const bf16x8*)kf0p;
        bf16x8 kf1 = *(const bf16x8*)kf1p;
        f32x16 St = mfma32(kf0, qb0, minit);
        St = mfma32(kf1, qb1, St);

        // P = exp2(St): regs 0..7 -> keys [0,16) of this kh-half (permuted), 8..15 -> [16,32)
        u16x8 p0u, p1u;
        #pragma unroll
        for (int j = 0; j < 8; j++) {
            p0u[j] = f2bf(__builtin_amdgcn_exp2f(St[j]));
            p1u[j] = f2bf(__builtin_amdgcn_exp2f(St[8 + j]));
        }
        bf16x8 pa0 = __builtin_bit_cast(bf16x8, p0u);
        bf16x8 pa1 = __builtin_bit_cast(bf16x8, p1u);

        lacc = mfma32(pa0, ones, lacc);      // rowsum(P) via ones-MFMA
        lacc = mfma32(pa1, ones, lacc);

        #pragma unroll
        for (int s2 = 0; s2 < 2; s2++) {
            bf16x8 pa = s2 ? pa1 : pa0;
            int slot = ((kh * 4 + s2 * 2 + h) ^ (ln & 7)) * 8;
            #pragma unroll
            for (int nt = 0; nt < 8; nt++) {
                bf16x8 vf = *(const bf16x8*)(lV + (nt * 32 + l31) * 64 + slot);
                Oacc[nt] = mfma32(pa, vf, Oacc[nt]);
            }
        }
        __syncthreads();   // protect lK/lV before next stage
    }

    // ---- cross-wave (key-half) combine via smem; kh=1 publishes, kh=0 reduces ----
    if (kh == 1) {
        #pragma unroll
        for (int nt = 0; nt < 8; nt++)
            #pragma unroll
            for (int rg = 0; rg < 2; rg++) {
                u16x8 pk;
                #pragma unroll
                for (int j = 0; j < 8; j++) pk[j] = f2bf(Oacc[nt][rg * 8 + j]);
                *(u16x8*)(smem + qh * 16384 + nt * 2048 + rg * 1024 + ln * 16) = pk;
            }
        #pragma unroll
        for (int rg = 0; rg < 4; rg++) {
            f32x4 lv;
            #pragma unroll
            for (int j = 0; j < 4; j++) lv[j] = lacc[rg * 4 + j];
            *(f32x4*)(smem + 32768 + qh * 4096 + rg * 1024 + ln * 16) = lv;
        }
    }
    __syncthreads();
    if (kh == 0) {
        float rl[16];
        #pragma unroll
        for (int rg = 0; rg < 4; rg++) {
            f32x4 lv = *(const f32x4*)(smem + 32768 + qh * 4096 + rg * 1024 + ln * 16);
            #pragma unroll
            for (int j = 0; j < 4; j++) rl[rg * 4 + j] = 1.f / (lacc[rg * 4 + j] + lv[j]);
        }
        size_t rb = (size_t)(b * 4096 + q0 + qh * 32);
        #pragma unroll
        for (int nt = 0; nt < 8; nt++)
            #pragma unroll
            for (int rg = 0; rg < 2; rg++) {
                u16x8 pk = *(const u16x8*)(smem + qh * 16384 + nt * 2048 + rg * 1024 + ln * 16);
                #pragma unroll
                for (int j = 0; j < 8; j++) {
                    int r = rg * 8 + j;
                    float val = (Oacc[nt][r] + bf2f(pk[j])) * rl[r];
                    int row = (r & 3) + 8 * (r >> 2) + 4 * h;
                    Oa[(rb + row) * 256 + nt * 32 + l31] = f2bf(val);
                }
            }
    }
}

// ---------------- launch ----------------
extern "C" void kernel_launch(void* const* d_in, const int* in_sizes, int n_in,
                              void* d_out, int out_size, void* d_ws, size_t ws_size,
                              hipStream_t stream) {
    const float* x  = (const float*)d_in[0];
    const float* nw = (const float*)d_in[1];
    const float* nb = (const float*)d_in[2];
    const float* wq = (const float*)d_in[3];
    const float* wk = (const float*)d_in[4];
    const float* wv = (const float*)d_in[5];
    const float* wp = (const float*)d_in[6];
    const float* gm = (const float*)d_in[7];

    char* p = (char*)d_ws;
    unsigned short* ht  = (unsigned short*)p; p += (size_t)32768 * 256 * 2;  // 16 MB
    unsigned short* qk  = (unsigned short*)p; p += (size_t)32768 * 64 * 2;   // 4 MB
    unsigned short* vt  = (unsigned short*)p; p += (size_t)8 * 256 * 4096 * 2; // 16 MB
    unsigned short* oa  = (unsigned short*)p; p += (size_t)32768 * 256 * 2;  // 16 MB
    unsigned short* bqk = (unsigned short*)p; p += 64 * 256 * 2;
    unsigned short* bv  = (unsigned short*)p; p += 256 * 256 * 2;
    unsigned short* bp  = (unsigned short*)p; p += 256 * 256 * 2;

    k_pack<<<dim3(256), dim3(256), 0, stream>>>(wq, wk, wv, wp, bqk, bv, bp);
    k_gnorm<<<dim3(256), dim3(1024), 0, stream>>>(x, nw, nb, ht);
    k_gemm<0><<<dim3(256, 1), dim3(256), 0, stream>>>(ht, bqk, (void*)qk, nullptr, nullptr, 64);
    k_gemm<1><<<dim3(256, 4), dim3(256), 0, stream>>>(ht, bv, (void*)vt, nullptr, nullptr, 0);
    k_flash<<<dim3(512), dim3(256), 0, stream>>>(qk, vt, oa);
    k_gemm<2><<<dim3(256, 4), dim3(256), 0, stream>>>(oa, bp, d_out, x, gm, 0);
}

// Round 5
// 234.357 us; speedup vs baseline: 1.7301x; 1.0076x over previous
//
#include <hip/hip_runtime.h>
#include <cstdint>

// Shapes: B=8, C=256, H=W=64 -> N=4096, d=32, groups=32 (8 ch/group)

typedef __bf16 bf16x8 __attribute__((ext_vector_type(8)));
typedef float f32x4 __attribute__((ext_vector_type(4)));
typedef float f32x16 __attribute__((ext_vector_type(16)));
typedef unsigned int u32x4 __attribute__((ext_vector_type(4)));
typedef unsigned short u16x4 __attribute__((ext_vector_type(4)));
typedef unsigned short u16x8 __attribute__((ext_vector_type(8)));

#define DEVI __device__ __forceinline__

DEVI unsigned short f2bf(float f) {
    __bf16 h = (__bf16)f;               // RNE fptrunc
    return __builtin_bit_cast(unsigned short, h);
}
DEVI float bf2f(unsigned short u) {
    unsigned int x = ((unsigned int)u) << 16;
    return __builtin_bit_cast(float, x);
}

DEVI f32x4 mfma16(bf16x8 a, bf16x8 b, f32x4 c) {
    return __builtin_amdgcn_mfma_f32_16x16x32_bf16(a, b, c, 0, 0, 0);
}
DEVI f32x16 mfma32(bf16x8 a, bf16x8 b, f32x16 c) {
    return __builtin_amdgcn_mfma_f32_32x32x16_bf16(a, b, c, 0, 0, 0);
}

// async global->LDS, 16B per lane, wave-uniform LDS base + lane*16
DEVI void glds16(const unsigned short* g, unsigned short* l) {
    const __attribute__((address_space(1))) unsigned int* gp =
        reinterpret_cast<const __attribute__((address_space(1))) unsigned int*>(
            reinterpret_cast<uintptr_t>(g));
    __attribute__((address_space(3))) unsigned int* lp =
        reinterpret_cast<__attribute__((address_space(3))) unsigned int*>(
            reinterpret_cast<uintptr_t>(l));
    __builtin_amdgcn_global_load_lds(gp, lp, 16, 0, 0);
}

// raw barrier without the compiler's vmcnt(0)-drain; manual waits only
DEVI void barrier_raw() {
    asm volatile("" ::: "memory");
    __builtin_amdgcn_s_barrier();
    asm volatile("" ::: "memory");
}
DEVI void wait_vm0() {
    // SIMM16: vmcnt[3:0]=0, expcnt[6:4]=7, lgkmcnt[13:8]=0x3F, vmcnt[5:4]=0
    __builtin_amdgcn_s_waitcnt(0x3F70);
}

// log2(e)/sqrt(32): folded into Wq so S exits QK-MFMA in exp2 domain
#define QSCALE 0.2550663133f
#define MFIX   12.0f

// ---------------- weight pack fp32 -> bf16 ----------------
__global__ __launch_bounds__(256) void k_pack(
        const float* __restrict__ wq, const float* __restrict__ wk,
        const float* __restrict__ wv, const float* __restrict__ wp,
        unsigned short* __restrict__ bqk, unsigned short* __restrict__ bv,
        unsigned short* __restrict__ bp) {
    int i = blockIdx.x * 256 + threadIdx.x;        // grid 256 -> 65536 threads
    if (i < 8192)       bqk[i] = f2bf(wq[i] * QSCALE);   // rows 0..31 = Wq (pre-scaled)
    else if (i < 16384) bqk[i] = f2bf(wk[i - 8192]);     // rows 32..63 = Wk
    bv[i] = f2bf(wv[i]);
    bp[i] = f2bf(wp[i]);
}

// ---------------- group norm -> h^T (B*N, C) bf16 ----------------
__global__ __launch_bounds__(1024) void k_gnorm(
        const float* __restrict__ x, const float* __restrict__ gw,
        const float* __restrict__ gb, unsigned short* __restrict__ ht) {
    int bg = blockIdx.x;               // 256 blocks = 8 batches * 32 groups
    int b = bg >> 5, g = bg & 31;
    const float* xb = x + ((size_t)(b * 256 + g * 8)) * 4096;  // 8 contiguous rows
    int t = threadIdx.x;
    float s1 = 0.f, s2 = 0.f;
    const f32x4* xv4 = (const f32x4*)xb;
    for (int i = t; i < 8192; i += 1024) {
        f32x4 v = xv4[i];
        #pragma unroll
        for (int j = 0; j < 4; j++) { s1 += v[j]; s2 += v[j] * v[j]; }
    }
    #pragma unroll
    for (int off = 1; off < 64; off <<= 1) {
        s1 += __shfl_xor(s1, off);
        s2 += __shfl_xor(s2, off);
    }
    __shared__ float red[34];
    int wv_ = t >> 6;
    if ((t & 63) == 0) { red[wv_ * 2] = s1; red[wv_ * 2 + 1] = s2; }
    __syncthreads();
    if (t == 0) {
        float a = 0.f, q = 0.f;
        #pragma unroll
        for (int i = 0; i < 16; i++) { a += red[i * 2]; q += red[i * 2 + 1]; }
        float mean = a * (1.f / 32768.f);
        float var = q * (1.f / 32768.f) - mean * mean;
        red[32] = mean; red[33] = rsqrtf(var + 1e-5f);
    }
    __syncthreads();
    float mean = red[32], rstd = red[33];
    float wv8[8], bv8[8];
    #pragma unroll
    for (int c = 0; c < 8; c++) { wv8[c] = gw[g * 8 + c] * rstd; bv8[c] = gb[g * 8 + c] - mean * rstd * gw[g * 8 + c]; }
    int n0 = t * 4;
    f32x4 cv[8];
    #pragma unroll
    for (int c = 0; c < 8; c++) cv[c] = *(const f32x4*)(xb + c * 4096 + n0);
    #pragma unroll
    for (int j = 0; j < 4; j++) {
        u16x8 pk;
        #pragma unroll
        for (int c = 0; c < 8; c++) pk[c] = f2bf(cv[c][j] * wv8[c] + bv8[c]);
        *(u16x8*)(&ht[((size_t)(b * 4096 + n0 + j)) * 256 + g * 8]) = pk;  // 16B store
    }
}

// ---------------- GEMM  C[M x Ncols] = A[M x 256] * Bw[Ncols x 256]^T ----------------
// EPI 0: bf16 row-major out (ldout).  EPI 1: bf16 transposed Vt[b][o][n] with
//        key-dim bit2<->bit3 swap per 16-group (PV A-frag permutation).
// EPI 2: fp32 transposed + residual: out[b][o][n] = x + gamma*acc.
template <int EPI>
__global__ __launch_bounds__(256) void k_gemm(
        const unsigned short* __restrict__ A, const unsigned short* __restrict__ Bw,
        void* __restrict__ outp, const float* __restrict__ xres,
        const float* __restrict__ gamma, int ldout) {
    __shared__ unsigned short lA[128 * 72];
    __shared__ unsigned short lB[64 * 72];
    int t = threadIdx.x;
    int m0 = blockIdx.x * 128, n0 = blockIdx.y * 64;
    int w = t >> 6, lane = t & 63, l15 = lane & 15, quad = lane >> 4;
    f32x4 z4 = {0.f, 0.f, 0.f, 0.f};
    f32x4 acc[2][4];
    #pragma unroll
    for (int i = 0; i < 2; i++)
        #pragma unroll
        for (int j = 0; j < 4; j++) acc[i][j] = z4;

    for (int kb = 0; kb < 4; kb++) {
        #pragma unroll
        for (int i = 0; i < 4; i++) {
            int ch = i * 256 + t;
            int row = ch >> 3, col = (ch & 7) * 8;
            u32x4 v = *(const u32x4*)(A + (size_t)(m0 + row) * 256 + kb * 64 + col);
            *(u32x4*)(&lA[row * 72 + col]) = v;
        }
        #pragma unroll
        for (int i = 0; i < 2; i++) {
            int ch = i * 256 + t;
            int row = ch >> 3, col = (ch & 7) * 8;
            u32x4 v = *(const u32x4*)(Bw + (size_t)(n0 + row) * 256 + kb * 64 + col);
            *(u32x4*)(&lB[row * 72 + col]) = v;
        }
        __syncthreads();
        #pragma unroll
        for (int ks = 0; ks < 2; ks++) {
            bf16x8 af[2], bfr[4];
            #pragma unroll
            for (int fr = 0; fr < 2; fr++)
                af[fr] = *(const bf16x8*)(&lA[(w * 32 + fr * 16 + l15) * 72 + ks * 32 + quad * 8]);
            #pragma unroll
            for (int fn = 0; fn < 4; fn++)
                bfr[fn] = *(const bf16x8*)(&lB[(fn * 16 + l15) * 72 + ks * 32 + quad * 8]);
            #pragma unroll
            for (int fr = 0; fr < 2; fr++)
                #pragma unroll
                for (int fn = 0; fn < 4; fn++)
                    acc[fr][fn] = mfma16(af[fr], bfr[fn], acc[fr][fn]);
        }
        __syncthreads();
    }

    if (EPI == 0) {
        unsigned short* out = (unsigned short*)outp;
        #pragma unroll
        for (int fr = 0; fr < 2; fr++)
            #pragma unroll
            for (int fn = 0; fn < 4; fn++)
                #pragma unroll
                for (int r = 0; r < 4; r++) {
                    int m = m0 + w * 32 + fr * 16 + quad * 4 + r;
                    int n = n0 + fn * 16 + l15;
                    out[(size_t)m * ldout + n] = f2bf(acc[fr][fn][r]);
                }
    } else if (EPI == 1) {
        unsigned short* out = (unsigned short*)outp;
        int b = m0 >> 12, nb = (m0 & 4095) + w * 32;
        int swq = ((quad & 1) << 1) | (quad >> 1);   // bit2<->bit3 swap of n within 16
        #pragma unroll
        for (int fr = 0; fr < 2; fr++)
            #pragma unroll
            for (int fn = 0; fn < 4; fn++) {
                int o = n0 + fn * 16 + l15;
                int n = nb + fr * 16 + swq * 4;
                u16x4 pk;
                #pragma unroll
                for (int r = 0; r < 4; r++) pk[r] = f2bf(acc[fr][fn][r]);
                *(u16x4*)(&out[(((size_t)(b * 256 + o)) << 12) + n]) = pk;
            }
    } else {
        float* out = (float*)outp;
        float gm = gamma[0];
        int b = m0 >> 12, nb = (m0 & 4095) + w * 32;
        #pragma unroll
        for (int fr = 0; fr < 2; fr++)
            #pragma unroll
            for (int fn = 0; fn < 4; fn++) {
                int o = n0 + fn * 16 + l15;
                int n = nb + fr * 16 + quad * 4;
                size_t base = (((size_t)(b * 256 + o)) << 12) + n;
                f32x4 xv = *(const f32x4*)(xres + base);
                f32x4 ov;
                #pragma unroll
                for (int r = 0; r < 4; r++) ov[r] = xv[r] + gm * acc[fr][fn][r];
                *(f32x4*)(out + base) = ov;
            }
    }
}

// ---------------- flash attention: 32x32 MFMA, double-buffered K/V staging ----
// QK: (B*N, 64) bf16 (q cols 0..31 pre-scaled, k cols 32..63).
// Vt: (B, 256, N) bf16, key-dim sigma-permuted (bit2<->bit3 per 16-group).
// Block: 64 q-rows, 4 waves = 2 q-halves x 2 key-halves; Bc=64, 64 tiles.
// Per iter: vmcnt(0) [waits only current tile's 9 glds, issued a full iter
// ago] -> raw s_barrier -> issue next tile's glds into other buffer ->
// compute. Prefetch stays in flight across the whole compute phase.
__global__ __launch_bounds__(256, 2) void k_flash(
        const unsigned short* __restrict__ QK, const unsigned short* __restrict__ Vt,
        unsigned short* __restrict__ Oa) {
    __shared__ __align__(16) char smem[73728];   // 2 x (4KB K + 32KB V)
    int id = blockIdx.x;
    int b = id & 7, qt = id >> 3;      // batch <-> XCD affinity
    int t = threadIdx.x, w = t >> 6, ln = t & 63;
    int l31 = ln & 31, h = ln >> 5;
    int qh = w >> 1, kh = w & 1;
    int q0 = qt * 64;

    // persistent Q B-frag: B[k=d][n=q]; lane: q=l31, d = s*16 + h*8 + j
    const unsigned short* qrow = QK + ((size_t)(b * 4096 + q0 + qh * 32 + l31)) * 64;
    bf16x8 qb0 = *(const bf16x8*)(qrow + h * 8);
    bf16x8 qb1 = *(const bf16x8*)(qrow + 16 + h * 8);

    // staging: K tile (wave w stages keys w*16..+16), chunk-swizzled for A-frag reads
    int cgK = (ln & 3) ^ ((ln >> 2) & 3) ^ ((ln >> 4) & 3);
    const unsigned short* gK = QK + ((size_t)(b * 4096 + w * 16 + (ln >> 2))) * 64 + 32 + cgK * 8;
    // V tile: wave w stages o-rows w*64..+64, chunk-swizzled (slot = chunk ^ (o&7))
    int vc8 = (ln & 7) ^ ((ln >> 3) & 7);
    const unsigned short* gV = Vt + (((size_t)(b * 256 + w * 64 + (ln >> 3))) << 12) + vc8 * 8;

    // double buffers
    unsigned short* lK0 = (unsigned short*)smem;
    unsigned short* lV0 = (unsigned short*)(smem + 4096);
    unsigned short* lK1 = (unsigned short*)(smem + 36864);
    unsigned short* lV1 = (unsigned short*)(smem + 36864 + 4096);
    unsigned short* sK0 = lK0 + w * 512;
    unsigned short* sV0 = lV0 + w * 4096;
    unsigned short* sK1 = lK1 + w * 512;
    unsigned short* sV1 = lV1 + w * 4096;

    u16x8 onesu = {0x3F80, 0x3F80, 0x3F80, 0x3F80, 0x3F80, 0x3F80, 0x3F80, 0x3F80};
    bf16x8 ones = __builtin_bit_cast(bf16x8, onesu);
    f32x16 z16;
    #pragma unroll
    for (int i = 0; i < 16; i++) z16[i] = 0.f;
    f32x16 minit;
    #pragma unroll
    for (int i = 0; i < 16; i++) minit[i] = -MFIX;
    f32x16 Oacc[8];
    #pragma unroll
    for (int i = 0; i < 8; i++) Oacc[i] = z16;
    f32x16 lacc = z16;

    // loop-invariant LDS read offsets
    int gl = (l31 & 3) ^ ((l31 >> 2) & 3);
    const unsigned short* kf0p0 = lK0 + (kh * 32 + l31) * 32 + ((0 + h) ^ gl) * 8;
    const unsigned short* kf1p0 = lK0 + (kh * 32 + l31) * 32 + ((2 + h) ^ gl) * 8;
    const unsigned short* kf0p1 = lK1 + (kh * 32 + l31) * 32 + ((0 + h) ^ gl) * 8;
    const unsigned short* kf1p1 = lK1 + (kh * 32 + l31) * 32 + ((2 + h) ^ gl) * 8;
    int slotA = ((kh * 4 + 0 * 2 + h) ^ (ln & 7)) * 8;
    int slotB = ((kh * 4 + 1 * 2 + h) ^ (ln & 7)) * 8;

    auto stage = [&](int kn, unsigned short* sK, unsigned short* sV) {
        glds16(gK + (size_t)kn * 4096, sK);
        #pragma unroll
        for (int j = 0; j < 8; j++)
            glds16(gV + ((size_t)j * 8 << 12) + kn * 64, sV + j * 512);
    };

    auto compute = [&](const unsigned short* kf0p, const unsigned short* kf1p,
                       const unsigned short* lV) {
        bf16x8 kf0 = *(const bf16x8*)kf0p;
        bf16x8 kf1 = *(const bf16x8*)kf1p;
        f32x16 St = mfma32(kf0, qb0, minit);
        St = mfma32(kf1, qb1, St);
        u16x8 p0u, p1u;
        #pragma unroll
        for (int j = 0; j < 8; j++) {
            p0u[j] = f2bf(__builtin_amdgcn_exp2f(St[j]));
            p1u[j] = f2bf(__builtin_amdgcn_exp2f(St[8 + j]));
        }
        bf16x8 pa0 = __builtin_bit_cast(bf16x8, p0u);
        bf16x8 pa1 = __builtin_bit_cast(bf16x8, p1u);
        lacc = mfma32(pa0, ones, lacc);
        lacc = mfma32(pa1, ones, lacc);
        #pragma unroll
        for (int nt = 0; nt < 8; nt++) {
            bf16x8 vf = *(const bf16x8*)(lV + (nt * 32 + l31) * 64 + slotA);
            Oacc[nt] = mfma32(pa0, vf, Oacc[nt]);
        }
        #pragma unroll
        for (int nt = 0; nt < 8; nt++) {
            bf16x8 vf = *(const bf16x8*)(lV + (nt * 32 + l31) * 64 + slotB);
            Oacc[nt] = mfma32(pa1, vf, Oacc[nt]);
        }
    };

    stage(0, sK0, sV0);                 // preload tile 0 into buf0
    for (int kt = 0; kt < 64; kt += 2) {
        // --- even tile: compute buf0, prefetch kt+1 into buf1 ---
        wait_vm0();                     // drain buf0's loads (issued 1 iter ago)
        barrier_raw();
        stage(kt + 1, sK1, sV1);
        compute(kf0p0, kf1p0, lV0);
        // --- odd tile: compute buf1, prefetch kt+2 into buf0 ---
        wait_vm0();
        barrier_raw();
        if (kt + 2 < 64) stage(kt + 2, sK0, sV0);
        compute(kf0p1, kf1p1, lV1);
    }
    __syncthreads();                    // all reads done before smem reuse

    // ---- cross-wave (key-half) combine via smem; kh=1 publishes, kh=0 reduces ----
    if (kh == 1) {
        #pragma unroll
        for (int nt = 0; nt < 8; nt++)
            #pragma unroll
            for (int rg = 0; rg < 2; rg++) {
                u16x8 pk;
                #pragma unroll
                for (int j = 0; j < 8; j++) pk[j] = f2bf(Oacc[nt][rg * 8 + j]);
                *(u16x8*)(smem + qh * 16384 + nt * 2048 + rg * 1024 + ln * 16) = pk;
            }
        #pragma unroll
        for (int rg = 0; rg < 4; rg++) {
            f32x4 lv;
            #pragma unroll
            for (int j = 0; j < 4; j++) lv[j] = lacc[rg * 4 + j];
            *(f32x4*)(smem + 32768 + qh * 4096 + rg * 1024 + ln * 16) = lv;
        }
    }
    __syncthreads();
    if (kh == 0) {
        float rl[16];
        #pragma unroll
        for (int rg = 0; rg < 4; rg++) {
            f32x4 lv = *(const f32x4*)(smem + 32768 + qh * 4096 + rg * 1024 + ln * 16);
            #pragma unroll
            for (int j = 0; j < 4; j++) rl[rg * 4 + j] = 1.f / (lacc[rg * 4 + j] + lv[j]);
        }
        size_t rb = (size_t)(b * 4096 + q0 + qh * 32);
        #pragma unroll
        for (int nt = 0; nt < 8; nt++)
            #pragma unroll
            for (int rg = 0; rg < 2; rg++) {
                u16x8 pk = *(const u16x8*)(smem + qh * 16384 + nt * 2048 + rg * 1024 + ln * 16);
                #pragma unroll
                for (int j = 0; j < 8; j++) {
                    int r = rg * 8 + j;
                    float val = (Oacc[nt][r] + bf2f(pk[j])) * rl[r];
                    int row = (r & 3) + 8 * (r >> 2) + 4 * h;
                    Oa[(rb + row) * 256 + nt * 32 + l31] = f2bf(val);
                }
            }
    }
}

// ---------------- launch ----------------
extern "C" void kernel_launch(void* const* d_in, const int* in_sizes, int n_in,
                              void* d_out, int out_size, void* d_ws, size_t ws_size,
                              hipStream_t stream) {
    const float* x  = (const float*)d_in[0];
    const float* nw = (const float*)d_in[1];
    const float* nb = (const float*)d_in[2];
    const float* wq = (const float*)d_in[3];
    const float* wk = (const float*)d_in[4];
    const float* wv = (const float*)d_in[5];
    const float* wp = (const float*)d_in[6];
    const float* gm = (const float*)d_in[7];

    char* p = (char*)d_ws;
    unsigned short* ht  = (unsigned short*)p; p += (size_t)32768 * 256 * 2;  // 16 MB
    unsigned short* qk  = (unsigned short*)p; p += (size_t)32768 * 64 * 2;   // 4 MB
    unsigned short* vt  = (unsigned short*)p; p += (size_t)8 * 256 * 4096 * 2; // 16 MB
    unsigned short* oa  = (unsigned short*)p; p += (size_t)32768 * 256 * 2;  // 16 MB
    unsigned short* bqk = (unsigned short*)p; p += 64 * 256 * 2;
    unsigned short* bv  = (unsigned short*)p; p += 256 * 256 * 2;
    unsigned short* bp  = (unsigned short*)p; p += 256 * 256 * 2;

    k_pack<<<dim3(256), dim3(256), 0, stream>>>(wq, wk, wv, wp, bqk, bv, bp);
    k_gnorm<<<dim3(256), dim3(1024), 0, stream>>>(x, nw, nb, ht);
    k_gemm<0><<<dim3(256, 1), dim3(256), 0, stream>>>(ht, bqk, (void*)qk, nullptr, nullptr, 64);
    k_gemm<1><<<dim3(256, 4), dim3(256), 0, stream>>>(ht, bv, (void*)vt, nullptr, nullptr, 0);
    k_flash<<<dim3(512), dim3(256), 0, stream>>>(qk, vt, oa);
    k_gemm<2><<<dim3(256, 4), dim3(256), 0, stream>>>(oa, bp, d_out, x, gm, 0);
}